// Round 4
// baseline (2472.680 us; speedup 1.0000x reference)
//
#include <hip/hip_runtime.h>

#define NB 8  // src buckets for L2-windowed sweep

// ---- monotonic float <-> uint mapping for atomicMax on floats ----
__device__ __forceinline__ unsigned fmap(float f) {
  unsigned u = __float_as_uint(f);
  return (u & 0x80000000u) ? ~u : (u | 0x80000000u);
}
__device__ __forceinline__ float funmap(unsigned m) {
  unsigned u = (m & 0x80000000u) ? (m ^ 0x80000000u) : ~m;
  return __uint_as_float(u);
}

// ---------- node GEMM: Y[N,M] = X[N,K] @ W[K,M] + b ----------
template <int K, int M>
__global__ __launch_bounds__(256) void node_gemm(
    const float* __restrict__ X, const float* __restrict__ W,
    const float* __restrict__ bias, float* __restrict__ Y) {
  constexpr int NPB = 16;
  constexpr int COLS4 = M / 4;
  constexpr int NG = 256 / COLS4;
  constexpr int RPN = NPB / NG;
  __shared__ float xs[NPB * K];
  const int tid = threadIdx.x;
  const int n0 = blockIdx.x * NPB;
  {
    const float4* X4 = reinterpret_cast<const float4*>(X + (size_t)n0 * K);
    float4* xs4 = reinterpret_cast<float4*>(xs);
    for (int i = tid; i < NPB * K / 4; i += 256) xs4[i] = X4[i];
  }
  __syncthreads();
  const int c4 = (tid % COLS4) * 4;
  const int r0 = (tid / COLS4) * RPN;
  float acc[RPN][4];
#pragma unroll
  for (int r = 0; r < RPN; ++r)
#pragma unroll
    for (int q = 0; q < 4; ++q) acc[r][q] = 0.f;

  for (int k = 0; k < K; k += 4) {
    float xv[RPN][4];
#pragma unroll
    for (int r = 0; r < RPN; ++r)
      *reinterpret_cast<float4*>(xv[r]) =
          *reinterpret_cast<const float4*>(&xs[(r0 + r) * K + k]);
#pragma unroll
    for (int j = 0; j < 4; ++j) {
      float wv[4];
      *reinterpret_cast<float4*>(wv) =
          *reinterpret_cast<const float4*>(&W[(size_t)(k + j) * M + c4]);
#pragma unroll
      for (int r = 0; r < RPN; ++r)
#pragma unroll
        for (int q = 0; q < 4; ++q)
          acc[r][q] = fmaf(xv[r][j], wv[q], acc[r][q]);
    }
  }
  float bv[4];
  *reinterpret_cast<float4*>(bv) = *reinterpret_cast<const float4*>(&bias[c4]);
#pragma unroll
  for (int r = 0; r < RPN; ++r) {
    float o[4];
#pragma unroll
    for (int q = 0; q < 4; ++q) o[q] = acc[r][q] + bv[q];
    *reinterpret_cast<float4*>(&Y[(size_t)(n0 + r0 + r) * M + c4]) =
        *reinterpret_cast<float4*>(o);
  }
}

// ---------- bucketed CSR build: key = dst*NB + src/bdiv ----------
__global__ void hist_b(const int* __restrict__ ei, int* __restrict__ kcnt,
                       int E, int bdiv) {
  int i = blockIdx.x * blockDim.x + threadIdx.x;
  if (i < E) atomicAdd(&kcnt[ei[E + i] * NB + ei[i] / bdiv], 1);
}

__global__ __launch_bounds__(1024) void blk_scan(
    const int* __restrict__ in, int* __restrict__ out1, int* __restrict__ bsum, int n) {
  __shared__ int buf[1024];
  const int tid = threadIdx.x;
  const int gid = blockIdx.x * 1024 + tid;
  int v = (gid < n) ? in[gid] : 0;
  buf[tid] = v;
  __syncthreads();
  for (int off = 1; off < 1024; off <<= 1) {
    int t = (tid >= off) ? buf[tid - off] : 0;
    __syncthreads();
    buf[tid] += t;
    __syncthreads();
  }
  if (gid < n) out1[gid] = buf[tid];
  if (tid == 1023) bsum[blockIdx.x] = buf[1023];
}

__global__ void scan_bsum(int* __restrict__ bsum, int nb) {
  if (blockIdx.x == 0 && threadIdx.x == 0) {
    int a = 0;
    for (int i = 0; i < nb; ++i) { a += bsum[i]; bsum[i] = a; }
  }
}

__global__ void add_off(int* __restrict__ kptr, const int* __restrict__ bsum, int n) {
  int gid = blockIdx.x * blockDim.x + threadIdx.x;
  if (gid == 0) kptr[0] = 0;
  if (gid < n) {
    int blk = gid >> 10;
    if (blk > 0) kptr[1 + gid] += bsum[blk - 1];
  }
}

__global__ void csr_fill_b(const int* __restrict__ ei, const int* __restrict__ kptr,
                           int* __restrict__ kfill, int* __restrict__ csr_src,
                           int* __restrict__ csr_eid, int E, int bdiv) {
  int i = blockIdx.x * blockDim.x + threadIdx.x;
  if (i < E) {
    int src = ei[i], dst = ei[E + i];
    int key = dst * NB + src / bdiv;
    int slot = kptr[key] + atomicAdd(&kfill[key], 1);
    csr_src[slot] = src;
    csr_eid[slot] = i;
  }
}

// permute edge_attr rows into CSR order (streamed reads in the sweep)
__global__ void ea_perm(const float* __restrict__ ea, const int* __restrict__ csr_eid,
                        float* __restrict__ ea_csr, int E) {
  int i = blockIdx.x * blockDim.x + threadIdx.x;
  if (i < E * 16) {
    int slot = i >> 4;
    ea_csr[i] = ea[((size_t)csr_eid[slot] << 4) + (i & 15)];
  }
}

// ---------- one edge of fused GATv2 (logit + online-softmax update) ----------
template <int GS>
__device__ __forceinline__ void gat_edge(
    const float4 a, const float ev, const float4 xv,
    const float (&wef)[16][4], const float (&attv)[4],
    float& m, float& s, float (&acc)[4]) {
  float mv[4] = {a.x + xv.x, a.y + xv.y, a.z + xv.z, a.w + xv.w};
#pragma unroll
  for (int k = 0; k < 16; ++k) {
    const float c = __shfl(ev, k);
#pragma unroll
    for (int q = 0; q < 4; ++q) mv[q] = fmaf(c, wef[k][q], mv[q]);
  }
  float l = 0.f;
#pragma unroll
  for (int q = 0; q < 4; ++q) {
    const float v = fmaxf(mv[q], 0.2f * mv[q]);  // leaky-relu
    l = fmaf(v, attv[q], l);
  }
#pragma unroll
  for (int off = 1; off < GS; off <<= 1) l += __shfl_xor(l, off);
  const float nm = fmaxf(m, l);
  const float sc = __expf(m - nm);
  const float pe = __expf(l - nm);
  m = nm;
  s = fmaf(s, sc, pe);
  acc[0] = fmaf(pe, a.x, acc[0] * sc);
  acc[1] = fmaf(pe, a.y, acc[1] * sc);
  acc[2] = fmaf(pe, a.z, acc[2] * sc);
  acc[3] = fmaf(pe, a.w, acc[3] * sc);
}

// ---------- persistent-wave bucket-sweep fused GATv2 ----------
// Each wave owns DPW consecutive dsts; state (m,s,acc,xr) in registers for the
// whole layer; all waves sweep src-buckets in the same order so concurrent
// gathers share an L2-sized window.
// MODE 0: concat -> out[dst*HCROW + colbase + lane*4] = acc/s + bias
// MODE 1: head-pair partial mean -> out[dst*128 + lane*4] (lanes 0..31)
template <int HCROW, int DPW, int MODE>
__global__ __launch_bounds__(256) void fused_gat_sweep(
    const float* __restrict__ xl, const float* __restrict__ xr,
    const float* __restrict__ ea_csr, const float* __restrict__ We,
    const float* __restrict__ att, const float* __restrict__ bias,
    const int* __restrict__ kptr, const int* __restrict__ csr_src,
    float* __restrict__ out, int N, int colbase) {
  constexpr int C = HCROW / 4;   // per-head dim (64 or 128)
  constexpr int GS = C / 4;      // lanes per head group (16 or 32)
  const int lane = threadIdx.x & 63;
  const int gw = (blockIdx.x * blockDim.x + threadIdx.x) >> 6;
  const int d0 = gw * DPW;
  if (d0 >= N) return;

  float wef[16][4];
#pragma unroll
  for (int k = 0; k < 16; ++k)
    *reinterpret_cast<float4*>(wef[k]) =
        *reinterpret_cast<const float4*>(&We[k * HCROW + colbase + lane * 4]);
  const int col0 = colbase + lane * 4;
  const int head = col0 / C;
  float attv[4];
  *reinterpret_cast<float4*>(attv) =
      *reinterpret_cast<const float4*>(&att[head * C + (col0 % C)]);
  const float4* xl4 = reinterpret_cast<const float4*>(xl);
  const float4* xr4 = reinterpret_cast<const float4*>(xr);
  const int rs4 = HCROW / 4;
  const int coff = col0 >> 2;
  const int l15 = lane & 15;

  float m[DPW], s[DPW], acc[DPW][4];
  float4 xrv[DPW];
#pragma unroll
  for (int di = 0; di < DPW; ++di) {
    m[di] = -__builtin_inff();
    s[di] = 0.f;
    acc[di][0] = acc[di][1] = acc[di][2] = acc[di][3] = 0.f;
    const int dst = d0 + di;
    if (dst < N) xrv[di] = xr4[(size_t)dst * rs4 + coff];
  }

  for (int b = 0; b < NB; ++b) {
#pragma unroll
    for (int di = 0; di < DPW; ++di) {
      const int dst = d0 + di;
      if (dst >= N) continue;
      int p = kptr[dst * NB + b];
      const int pend = kptr[dst * NB + b + 1];
      const float4 xv = xrv[di];
      for (; p + 1 < pend; p += 2) {
        const int s0 = csr_src[p], s1 = csr_src[p + 1];
        const float e0 = ea_csr[(size_t)p * 16 + l15];
        const float e1 = ea_csr[((size_t)p + 1) * 16 + l15];
        const float4 a0 = xl4[(size_t)s0 * rs4 + coff];
        const float4 a1 = xl4[(size_t)s1 * rs4 + coff];
        gat_edge<GS>(a0, e0, xv, wef, attv, m[di], s[di], acc[di]);
        gat_edge<GS>(a1, e1, xv, wef, attv, m[di], s[di], acc[di]);
      }
      if (p < pend) {
        const int s0 = csr_src[p];
        const float e0 = ea_csr[(size_t)p * 16 + l15];
        const float4 a0 = xl4[(size_t)s0 * rs4 + coff];
        gat_edge<GS>(a0, e0, xv, wef, attv, m[di], s[di], acc[di]);
      }
    }
  }

  // epilogue
#pragma unroll
  for (int di = 0; di < DPW; ++di) {
    const int dst = d0 + di;
    if (dst >= N) continue;
    const float inv = 1.f / (s[di] + 1e-16f);
    float o[4];
    if (MODE == 0) {
      float bv[4];
      *reinterpret_cast<float4*>(bv) = *reinterpret_cast<const float4*>(&bias[col0]);
#pragma unroll
      for (int q = 0; q < 4; ++q) o[q] = fmaf(acc[di][q], inv, bv[q]);
      *reinterpret_cast<float4*>(&out[(size_t)dst * HCROW + col0]) =
          *reinterpret_cast<float4*>(o);
    } else {
#pragma unroll
      for (int q = 0; q < 4; ++q) {
        o[q] = acc[di][q] * inv;
        o[q] += __shfl_xor(o[q], 32);  // head h + head h+1 at same within-head col
      }
      if (lane < 32)
        *reinterpret_cast<float4*>(&out[(size_t)dst * 128 + lane * 4]) =
            *reinterpret_cast<float4*>(o);
    }
  }
}

// ---------- pooling (mean-over-heads + bias fused in) ----------
__global__ void pool_scatter(const float* __restrict__ hA, const float* __restrict__ hB,
                             const float* __restrict__ bias2, const int* __restrict__ batch,
                             unsigned* __restrict__ pmax, float* __restrict__ psum,
                             float* __restrict__ cnt, int N) {
  int idx = blockIdx.x * blockDim.x + threadIdx.x;
  if (idx >= N * 128) return;
  int n = idx >> 7, c = idx & 127;
  int g = batch[n];
  float v = 0.25f * (hA[idx] + hB[idx]) + bias2[c];
  atomicMax(&pmax[g * 128 + c], fmap(v));
  atomicAdd(&psum[g * 128 + c], v);
  if (c == 0) atomicAdd(&cnt[g], 1.f);
}

__global__ void pool_final(const unsigned* __restrict__ pmax, const float* __restrict__ psum,
                           const float* __restrict__ cnt, float* __restrict__ out) {
  int idx = blockIdx.x * blockDim.x + threadIdx.x;
  if (idx >= 64 * 128) return;
  int g = idx >> 7, c = idx & 127;
  float cg = cnt[g];
  out[g * 256 + c] = (cg > 0.f) ? funmap(pmax[idx]) : 0.f;
  out[g * 256 + 128 + c] = psum[idx] / fmaxf(cg, 1.f);
}

extern "C" void kernel_launch(void* const* d_in, const int* in_sizes, int n_in,
                              void* d_out, int out_size, void* d_ws, size_t ws_size,
                              hipStream_t stream) {
  const float* x     = (const float*)d_in[0];
  const float* ea    = (const float*)d_in[1];
  const int*   ei    = (const int*)d_in[2];
  const int*   batch = (const int*)d_in[3];
  const int N = in_sizes[0] / 128;  // 20000
  const int E = in_sizes[2] / 2;    // 640000
  const int NBINS = N * NB;
  const int bdiv = (N + NB - 1) / NB;  // 2500

  const float* Wl[3]   = {(const float*)d_in[4],  (const float*)d_in[11], (const float*)d_in[18]};
  const float* blv[3]  = {(const float*)d_in[5],  (const float*)d_in[12], (const float*)d_in[19]};
  const float* Wr[3]   = {(const float*)d_in[6],  (const float*)d_in[13], (const float*)d_in[20]};
  const float* brv[3]  = {(const float*)d_in[7],  (const float*)d_in[14], (const float*)d_in[21]};
  const float* Wev[3]  = {(const float*)d_in[8],  (const float*)d_in[15], (const float*)d_in[22]};
  const float* attv[3] = {(const float*)d_in[9],  (const float*)d_in[16], (const float*)d_in[23]};
  const float* bias[3] = {(const float*)d_in[10], (const float*)d_in[17], (const float*)d_in[24]};

  // ---- workspace layout (floats) ----
  float* ws = (float*)d_ws;
  float* xl     = ws;                          // N*512
  float* xr     = xl + (size_t)N * 512;        // N*512
  float* ea_csr = xr + (size_t)N * 512;        // E*16
  float* h      = ea_csr + (size_t)E * 16;     // N*256 (also build-temp ints; also hsumA/B)
  int* kptr     = (int*)(h + (size_t)N * 256); // NBINS+1
  int* csr_src  = kptr + (NBINS + 1);          // E
  int* bsum     = csr_src + E;                 // <=257
  unsigned* pmax = (unsigned*)(bsum + 257);    // 64*128
  float* psum   = (float*)(pmax + 64 * 128);   // 64*128
  float* cnt    = psum + 64 * 128;             // 64
  // build-time temps aliased inside h (dead before h is first written):
  int* csr_eid = (int*)h;                      // E
  int* kcnt    = csr_eid + E;                  // NBINS
  int* kfill   = kcnt + NBINS;                 // NBINS
  // layer-2 head-pair partial sums aliased inside h (h dead after L2 GEMMs):
  float* hsumA = h;                            // N*128
  float* hsumB = h + (size_t)N * 128;          // N*128
  (void)n_in; (void)out_size; (void)ws_size;

  const int nodeBlocks = N / 16;
  const int edgeBlocks = (E + 255) / 256;
  const int scanBlocks = (NBINS + 1023) / 1024;

  // ---- bucketed CSR build ----
  hipMemsetAsync(kcnt, 0, (size_t)2 * NBINS * sizeof(int), stream);  // kcnt+kfill
  hist_b<<<edgeBlocks, 256, 0, stream>>>(ei, kcnt, E, bdiv);
  blk_scan<<<scanBlocks, 1024, 0, stream>>>(kcnt, kptr + 1, bsum, NBINS);
  scan_bsum<<<1, 64, 0, stream>>>(bsum, scanBlocks);
  add_off<<<(NBINS + 255) / 256, 256, 0, stream>>>(kptr, bsum, NBINS);
  csr_fill_b<<<edgeBlocks, 256, 0, stream>>>(ei, kptr, kfill, csr_src, csr_eid, E, bdiv);
  ea_perm<<<(E * 16 + 255) / 256, 256, 0, stream>>>(ea, csr_eid, ea_csr, E);

  // ================= layer 0 (K=128 -> hc=256, concat) =================
  node_gemm<128, 256><<<nodeBlocks, 256, 0, stream>>>(x, Wl[0], blv[0], xl);
  node_gemm<128, 256><<<nodeBlocks, 256, 0, stream>>>(x, Wr[0], brv[0], xr);
  fused_gat_sweep<256, 10, 0><<<512, 256, 0, stream>>>(
      xl, xr, ea_csr, Wev[0], attv[0], bias[0], kptr, csr_src, h, N, 0);

  // ================= layer 1 (K=256 -> hc=256, concat) =================
  node_gemm<256, 256><<<nodeBlocks, 256, 0, stream>>>(h, Wl[1], blv[1], xl);
  node_gemm<256, 256><<<nodeBlocks, 256, 0, stream>>>(h, Wr[1], brv[1], xr);
  fused_gat_sweep<256, 10, 0><<<512, 256, 0, stream>>>(
      xl, xr, ea_csr, Wev[1], attv[1], bias[1], kptr, csr_src, h, N, 0);

  // ================= layer 2 (K=256 -> hc=512, mean over heads) =================
  node_gemm<256, 512><<<nodeBlocks, 256, 0, stream>>>(h, Wl[2], blv[2], xl);
  node_gemm<256, 512><<<nodeBlocks, 256, 0, stream>>>(h, Wr[2], brv[2], xr);
  // two column-half dispatches; each writes head-pair partial means
  fused_gat_sweep<512, 10, 1><<<512, 256, 0, stream>>>(
      xl, xr, ea_csr, Wev[2], attv[2], bias[2], kptr, csr_src, hsumA, N, 0);
  fused_gat_sweep<512, 10, 1><<<512, 256, 0, stream>>>(
      xl, xr, ea_csr, Wev[2], attv[2], bias[2], kptr, csr_src, hsumB, N, 256);

  // ================= pooling (mean-over-heads fused) =================
  hipMemsetAsync(pmax, 0, (size_t)(64 * 128 * 2 + 64) * sizeof(float), stream);
  pool_scatter<<<(N * 128 + 255) / 256, 256, 0, stream>>>(hsumA, hsumB, bias[2], batch,
                                                          pmax, psum, cnt, N);
  pool_final<<<(64 * 128 + 255) / 256, 256, 0, stream>>>(pmax, psum, cnt, (float*)d_out);
}

// Round 5
// 1348.769 us; speedup vs baseline: 1.8333x; 1.8333x over previous
//
#include <hip/hip_runtime.h>

#define NB 8  // src buckets: edges of each dst are stored bucket-sorted

// ---- monotonic float <-> uint mapping for atomicMax on floats ----
__device__ __forceinline__ unsigned fmap(float f) {
  unsigned u = __float_as_uint(f);
  return (u & 0x80000000u) ? ~u : (u | 0x80000000u);
}
__device__ __forceinline__ float funmap(unsigned m) {
  unsigned u = (m & 0x80000000u) ? (m ^ 0x80000000u) : ~m;
  return __uint_as_float(u);
}

// ---------- node GEMM: Y[N,M] = X[N,K] @ W[K,M] + b ----------
template <int K, int M>
__global__ __launch_bounds__(256) void node_gemm(
    const float* __restrict__ X, const float* __restrict__ W,
    const float* __restrict__ bias, float* __restrict__ Y) {
  constexpr int NPB = 16;
  constexpr int COLS4 = M / 4;
  constexpr int NG = 256 / COLS4;
  constexpr int RPN = NPB / NG;
  __shared__ float xs[NPB * K];
  const int tid = threadIdx.x;
  const int n0 = blockIdx.x * NPB;
  {
    const float4* X4 = reinterpret_cast<const float4*>(X + (size_t)n0 * K);
    float4* xs4 = reinterpret_cast<float4*>(xs);
    for (int i = tid; i < NPB * K / 4; i += 256) xs4[i] = X4[i];
  }
  __syncthreads();
  const int c4 = (tid % COLS4) * 4;
  const int r0 = (tid / COLS4) * RPN;
  float acc[RPN][4];
#pragma unroll
  for (int r = 0; r < RPN; ++r)
#pragma unroll
    for (int q = 0; q < 4; ++q) acc[r][q] = 0.f;

  for (int k = 0; k < K; k += 4) {
    float xv[RPN][4];
#pragma unroll
    for (int r = 0; r < RPN; ++r)
      *reinterpret_cast<float4*>(xv[r]) =
          *reinterpret_cast<const float4*>(&xs[(r0 + r) * K + k]);
#pragma unroll
    for (int j = 0; j < 4; ++j) {
      float wv[4];
      *reinterpret_cast<float4*>(wv) =
          *reinterpret_cast<const float4*>(&W[(size_t)(k + j) * M + c4]);
#pragma unroll
      for (int r = 0; r < RPN; ++r)
#pragma unroll
        for (int q = 0; q < 4; ++q)
          acc[r][q] = fmaf(xv[r][j], wv[q], acc[r][q]);
    }
  }
  float bv[4];
  *reinterpret_cast<float4*>(bv) = *reinterpret_cast<const float4*>(&bias[c4]);
#pragma unroll
  for (int r = 0; r < RPN; ++r) {
    float o[4];
#pragma unroll
    for (int q = 0; q < 4; ++q) o[q] = acc[r][q] + bv[q];
    *reinterpret_cast<float4*>(&Y[(size_t)(n0 + r0 + r) * M + c4]) =
        *reinterpret_cast<float4*>(o);
  }
}

// ---------- bucketed CSR build: key = dst*NB + src/bdiv ----------
__global__ void hist_b(const int* __restrict__ ei, int* __restrict__ kcnt,
                       int E, int bdiv) {
  int i = blockIdx.x * blockDim.x + threadIdx.x;
  if (i < E) atomicAdd(&kcnt[ei[E + i] * NB + ei[i] / bdiv], 1);
}

__global__ __launch_bounds__(1024) void blk_scan(
    const int* __restrict__ in, int* __restrict__ out1, int* __restrict__ bsum, int n) {
  __shared__ int buf[1024];
  const int tid = threadIdx.x;
  const int gid = blockIdx.x * 1024 + tid;
  int v = (gid < n) ? in[gid] : 0;
  buf[tid] = v;
  __syncthreads();
  for (int off = 1; off < 1024; off <<= 1) {
    int t = (tid >= off) ? buf[tid - off] : 0;
    __syncthreads();
    buf[tid] += t;
    __syncthreads();
  }
  if (gid < n) out1[gid] = buf[tid];
  if (tid == 1023) bsum[blockIdx.x] = buf[1023];
}

__global__ void scan_bsum(int* __restrict__ bsum, int nb) {
  if (blockIdx.x == 0 && threadIdx.x == 0) {
    int a = 0;
    for (int i = 0; i < nb; ++i) { a += bsum[i]; bsum[i] = a; }
  }
}

__global__ void add_off(int* __restrict__ kptr, const int* __restrict__ bsum, int n) {
  int gid = blockIdx.x * blockDim.x + threadIdx.x;
  if (gid == 0) kptr[0] = 0;
  if (gid < n) {
    int blk = gid >> 10;
    if (blk > 0) kptr[1 + gid] += bsum[blk - 1];
  }
}

__global__ void csr_fill_b(const int* __restrict__ ei, const int* __restrict__ kptr,
                           int* __restrict__ kfill, int* __restrict__ csr_src,
                           int* __restrict__ csr_eid, int E, int bdiv) {
  int i = blockIdx.x * blockDim.x + threadIdx.x;
  if (i < E) {
    int src = ei[i], dst = ei[E + i];
    int key = dst * NB + src / bdiv;
    int slot = kptr[key] + atomicAdd(&kfill[key], 1);
    csr_src[slot] = src;
    csr_eid[slot] = i;
  }
}

// permute edge_attr rows into CSR order (streamed reads in the fused kernel)
__global__ void ea_perm(const float* __restrict__ ea, const int* __restrict__ csr_eid,
                        float* __restrict__ ea_csr, int E) {
  int i = blockIdx.x * blockDim.x + threadIdx.x;
  if (i < E * 16) {
    int slot = i >> 4;
    ea_csr[i] = ea[((size_t)csr_eid[slot] << 4) + (i & 15)];
  }
}

// ---------- one edge of fused GATv2 (logit + online-softmax update) ----------
template <int GS>
__device__ __forceinline__ void gat_edge(
    const float4 a, const float ev, const float4 xv,
    const float (&wef)[16][4], const float (&attv)[4],
    float& m, float& s, float (&acc)[4]) {
  float mv[4] = {a.x + xv.x, a.y + xv.y, a.z + xv.z, a.w + xv.w};
#pragma unroll
  for (int k = 0; k < 16; ++k) {
    const float c = __shfl(ev, k);
#pragma unroll
    for (int q = 0; q < 4; ++q) mv[q] = fmaf(c, wef[k][q], mv[q]);
  }
  float l = 0.f;
#pragma unroll
  for (int q = 0; q < 4; ++q) {
    const float v = fmaxf(mv[q], 0.2f * mv[q]);  // leaky-relu
    l = fmaf(v, attv[q], l);
  }
#pragma unroll
  for (int off = 1; off < GS; off <<= 1) l += __shfl_xor(l, off);
  const float nm = fmaxf(m, l);
  const float sc = __expf(m - nm);
  const float pe = __expf(l - nm);
  m = nm;
  s = fmaf(s, sc, pe);
  acc[0] = fmaf(pe, a.x, acc[0] * sc);
  acc[1] = fmaf(pe, a.y, acc[1] * sc);
  acc[2] = fmaf(pe, a.z, acc[2] * sc);
  acc[3] = fmaf(pe, a.w, acc[3] * sc);
}

// ---------- fused per-dst GATv2: wave-per-dst, bucket-sorted edge lists ----------
// One wave owns one dst (256-column slab selected by colbase). Edges arrive
// bucket-sorted, so concurrently-resident waves gather from a narrow src window.
// MODE 0: concat -> out[dst*HCROW + col0] = acc/s + bias
// MODE 1: head-pair partial mean -> out[dst*128 + lane*4] (lanes 0..31)
template <int HCROW, int MODE>
__global__ __launch_bounds__(256) void fused_gat(
    const float* __restrict__ xl, const float* __restrict__ xr,
    const float* __restrict__ ea_csr, const float* __restrict__ We,
    const float* __restrict__ att, const float* __restrict__ bias,
    const int* __restrict__ kptr, const int* __restrict__ csr_src,
    float* __restrict__ out, int N, int colbase) {
  constexpr int C = HCROW / 4;   // per-head dim (64 or 128)
  constexpr int GS = C / 4;      // lanes per head group (16 or 32)
  const int lane = threadIdx.x & 63;
  const int wslot = threadIdx.x >> 6;
  const int dst = blockIdx.x * 4 + wslot;
  if (dst >= N) return;

  float wef[16][4];
#pragma unroll
  for (int k = 0; k < 16; ++k)
    *reinterpret_cast<float4*>(wef[k]) =
        *reinterpret_cast<const float4*>(&We[k * HCROW + colbase + lane * 4]);
  const int col0 = colbase + lane * 4;
  const int head = col0 / C;
  float attv[4];
  *reinterpret_cast<float4*>(attv) =
      *reinterpret_cast<const float4*>(&att[head * C + (col0 % C)]);
  const float4* xl4 = reinterpret_cast<const float4*>(xl);
  const int rs4 = HCROW / 4;
  const int coff = col0 >> 2;
  const float4 xrv =
      reinterpret_cast<const float4*>(xr)[(size_t)dst * rs4 + coff];
  const int l15 = lane & 15;

  const int row0 = kptr[dst * NB];
  const int deg = kptr[dst * NB + NB] - row0;

  float m = -__builtin_inff(), s = 0.f;
  float acc[4] = {0.f, 0.f, 0.f, 0.f};

  for (int cs = 0; cs < deg; cs += 64) {
    const int cn = min(64, deg - cs);
    const int base = row0 + cs;
    const int srcv = (lane < cn) ? csr_src[base + lane] : 0;

    // prime the 2-edge pipeline
    const int i1 = (cn > 1) ? 1 : 0;
    int sA = __shfl(srcv, 0);
    int sB = __shfl(srcv, i1);
    float4 a0 = xl4[(size_t)sA * rs4 + coff];
    float ev0 = ea_csr[(size_t)base * 16 + l15];
    float4 a1 = xl4[(size_t)sB * rs4 + coff];
    float ev1 = ea_csr[(size_t)(base + i1) * 16 + l15];

    for (int j = 0; j < cn; j += 2) {
      // prefetch edges j+2, j+3 (clamped; dup loads past end are discarded)
      const int pA = min(j + 2, cn - 1), pB = min(j + 3, cn - 1);
      const int snA = __shfl(srcv, pA);
      const int snB = __shfl(srcv, pB);
      const float4 anA = xl4[(size_t)snA * rs4 + coff];
      const float evnA = ea_csr[(size_t)(base + pA) * 16 + l15];
      const float4 anB = xl4[(size_t)snB * rs4 + coff];
      const float evnB = ea_csr[(size_t)(base + pB) * 16 + l15];

      gat_edge<GS>(a0, ev0, xrv, wef, attv, m, s, acc);
      if (j + 1 < cn) gat_edge<GS>(a1, ev1, xrv, wef, attv, m, s, acc);

      a0 = anA; ev0 = evnA;
      a1 = anB; ev1 = evnB;
    }
  }

  const float inv = 1.f / (s + 1e-16f);
  float o[4];
  if (MODE == 0) {
    float bv[4];
    *reinterpret_cast<float4*>(bv) = *reinterpret_cast<const float4*>(&bias[col0]);
#pragma unroll
    for (int q = 0; q < 4; ++q) o[q] = fmaf(acc[q], inv, bv[q]);
    *reinterpret_cast<float4*>(&out[(size_t)dst * HCROW + col0]) =
        *reinterpret_cast<float4*>(o);
  } else {
#pragma unroll
    for (int q = 0; q < 4; ++q) {
      o[q] = acc[q] * inv;
      o[q] += __shfl_xor(o[q], 32);  // combine the slab's two heads
    }
    if (lane < 32)
      *reinterpret_cast<float4*>(&out[(size_t)dst * 128 + lane * 4]) =
          *reinterpret_cast<float4*>(o);
  }
}

// ---------- pooling (mean-over-heads + bias fused in) ----------
__global__ void pool_scatter(const float* __restrict__ hA, const float* __restrict__ hB,
                             const float* __restrict__ bias2, const int* __restrict__ batch,
                             unsigned* __restrict__ pmax, float* __restrict__ psum,
                             float* __restrict__ cnt, int N) {
  int idx = blockIdx.x * blockDim.x + threadIdx.x;
  if (idx >= N * 128) return;
  int n = idx >> 7, c = idx & 127;
  int g = batch[n];
  float v = 0.25f * (hA[idx] + hB[idx]) + bias2[c];
  atomicMax(&pmax[g * 128 + c], fmap(v));
  atomicAdd(&psum[g * 128 + c], v);
  if (c == 0) atomicAdd(&cnt[g], 1.f);
}

__global__ void pool_final(const unsigned* __restrict__ pmax, const float* __restrict__ psum,
                           const float* __restrict__ cnt, float* __restrict__ out) {
  int idx = blockIdx.x * blockDim.x + threadIdx.x;
  if (idx >= 64 * 128) return;
  int g = idx >> 7, c = idx & 127;
  float cg = cnt[g];
  out[g * 256 + c] = (cg > 0.f) ? funmap(pmax[idx]) : 0.f;
  out[g * 256 + 128 + c] = psum[idx] / fmaxf(cg, 1.f);
}

extern "C" void kernel_launch(void* const* d_in, const int* in_sizes, int n_in,
                              void* d_out, int out_size, void* d_ws, size_t ws_size,
                              hipStream_t stream) {
  const float* x     = (const float*)d_in[0];
  const float* ea    = (const float*)d_in[1];
  const int*   ei    = (const int*)d_in[2];
  const int*   batch = (const int*)d_in[3];
  const int N = in_sizes[0] / 128;  // 20000
  const int E = in_sizes[2] / 2;    // 640000
  const int NBINS = N * NB;
  const int bdiv = (N + NB - 1) / NB;  // 2500

  const float* Wl[3]   = {(const float*)d_in[4],  (const float*)d_in[11], (const float*)d_in[18]};
  const float* blv[3]  = {(const float*)d_in[5],  (const float*)d_in[12], (const float*)d_in[19]};
  const float* Wr[3]   = {(const float*)d_in[6],  (const float*)d_in[13], (const float*)d_in[20]};
  const float* brv[3]  = {(const float*)d_in[7],  (const float*)d_in[14], (const float*)d_in[21]};
  const float* Wev[3]  = {(const float*)d_in[8],  (const float*)d_in[15], (const float*)d_in[22]};
  const float* attv[3] = {(const float*)d_in[9],  (const float*)d_in[16], (const float*)d_in[23]};
  const float* bias[3] = {(const float*)d_in[10], (const float*)d_in[17], (const float*)d_in[24]};

  // ---- workspace layout (floats) ----
  float* ws = (float*)d_ws;
  float* xl     = ws;                          // N*512
  float* xr     = xl + (size_t)N * 512;        // N*512
  float* ea_csr = xr + (size_t)N * 512;        // E*16
  float* h      = ea_csr + (size_t)E * 16;     // N*256 (aliased: build ints / hsumA,B)
  int* kptr     = (int*)(h + (size_t)N * 256); // NBINS+1
  int* csr_src  = kptr + (NBINS + 1);          // E
  int* bsum     = csr_src + E;                 // <=257
  unsigned* pmax = (unsigned*)(bsum + 257);    // 64*128
  float* psum   = (float*)(pmax + 64 * 128);   // 64*128
  float* cnt    = psum + 64 * 128;             // 64
  // build-time temps aliased inside h (dead before h is first written):
  int* csr_eid = (int*)h;                      // E
  int* kcnt    = csr_eid + E;                  // NBINS
  int* kfill   = kcnt + NBINS;                 // NBINS
  // layer-2 head-pair partial sums aliased inside h (h dead after L2 GEMMs):
  float* hsumA = h;                            // N*128
  float* hsumB = h + (size_t)N * 128;          // N*128
  (void)n_in; (void)out_size; (void)ws_size;

  const int nodeBlocks = N / 16;
  const int edgeBlocks = (E + 255) / 256;
  const int scanBlocks = (NBINS + 1023) / 1024;
  const int gatBlocks = (N + 3) / 4;  // 4 waves/block, wave-per-dst

  // ---- bucketed CSR build ----
  hipMemsetAsync(kcnt, 0, (size_t)2 * NBINS * sizeof(int), stream);  // kcnt+kfill
  hist_b<<<edgeBlocks, 256, 0, stream>>>(ei, kcnt, E, bdiv);
  blk_scan<<<scanBlocks, 1024, 0, stream>>>(kcnt, kptr + 1, bsum, NBINS);
  scan_bsum<<<1, 64, 0, stream>>>(bsum, scanBlocks);
  add_off<<<(NBINS + 255) / 256, 256, 0, stream>>>(kptr, bsum, NBINS);
  csr_fill_b<<<edgeBlocks, 256, 0, stream>>>(ei, kptr, kfill, csr_src, csr_eid, E, bdiv);
  ea_perm<<<(E * 16 + 255) / 256, 256, 0, stream>>>(ea, csr_eid, ea_csr, E);

  // ================= layer 0 (K=128 -> hc=256, concat) =================
  node_gemm<128, 256><<<nodeBlocks, 256, 0, stream>>>(x, Wl[0], blv[0], xl);
  node_gemm<128, 256><<<nodeBlocks, 256, 0, stream>>>(x, Wr[0], brv[0], xr);
  fused_gat<256, 0><<<gatBlocks, 256, 0, stream>>>(
      xl, xr, ea_csr, Wev[0], attv[0], bias[0], kptr, csr_src, h, N, 0);

  // ================= layer 1 (K=256 -> hc=256, concat) =================
  node_gemm<256, 256><<<nodeBlocks, 256, 0, stream>>>(h, Wl[1], blv[1], xl);
  node_gemm<256, 256><<<nodeBlocks, 256, 0, stream>>>(h, Wr[1], brv[1], xr);
  fused_gat<256, 0><<<gatBlocks, 256, 0, stream>>>(
      xl, xr, ea_csr, Wev[1], attv[1], bias[1], kptr, csr_src, h, N, 0);

  // ================= layer 2 (K=256 -> hc=512, mean over heads) =================
  node_gemm<256, 512><<<nodeBlocks, 256, 0, stream>>>(h, Wl[2], blv[2], xl);
  node_gemm<256, 512><<<nodeBlocks, 256, 0, stream>>>(h, Wr[2], brv[2], xr);
  // two column-half dispatches; each writes head-pair partial means
  fused_gat<512, 1><<<gatBlocks, 256, 0, stream>>>(
      xl, xr, ea_csr, Wev[2], attv[2], bias[2], kptr, csr_src, hsumA, N, 0);
  fused_gat<512, 1><<<gatBlocks, 256, 0, stream>>>(
      xl, xr, ea_csr, Wev[2], attv[2], bias[2], kptr, csr_src, hsumB, N, 256);

  // ================= pooling (mean-over-heads fused) =================
  hipMemsetAsync(pmax, 0, (size_t)(64 * 128 * 2 + 64) * sizeof(float), stream);
  pool_scatter<<<(N * 128 + 255) / 256, 256, 0, stream>>>(hsumA, hsumB, bias[2], batch,
                                                          pmax, psum, cnt, N);
  pool_final<<<(64 * 128 + 255) / 256, 256, 0, stream>>>(pmax, psum, cnt, (float*)d_out);
}

// Round 6
// 1118.576 us; speedup vs baseline: 2.2106x; 1.2058x over previous
//
#include <hip/hip_runtime.h>

#define NB 8  // src buckets: edges of each dst are stored bucket-sorted

// ---- monotonic float <-> uint mapping for atomicMax on floats ----
__device__ __forceinline__ unsigned fmap(float f) {
  unsigned u = __float_as_uint(f);
  return (u & 0x80000000u) ? ~u : (u | 0x80000000u);
}
__device__ __forceinline__ float funmap(unsigned m) {
  unsigned u = (m & 0x80000000u) ? (m ^ 0x80000000u) : ~m;
  return __uint_as_float(u);
}

// ---------- node GEMM: Y[N,M] = X[N,K] @ W[K,M] + b ----------
template <int K, int M>
__global__ __launch_bounds__(256) void node_gemm(
    const float* __restrict__ X, const float* __restrict__ W,
    const float* __restrict__ bias, float* __restrict__ Y) {
  constexpr int NPB = 16;
  constexpr int COLS4 = M / 4;
  constexpr int NG = 256 / COLS4;
  constexpr int RPN = NPB / NG;
  __shared__ float xs[NPB * K];
  const int tid = threadIdx.x;
  const int n0 = blockIdx.x * NPB;
  {
    const float4* X4 = reinterpret_cast<const float4*>(X + (size_t)n0 * K);
    float4* xs4 = reinterpret_cast<float4*>(xs);
    for (int i = tid; i < NPB * K / 4; i += 256) xs4[i] = X4[i];
  }
  __syncthreads();
  const int c4 = (tid % COLS4) * 4;
  const int r0 = (tid / COLS4) * RPN;
  float acc[RPN][4];
#pragma unroll
  for (int r = 0; r < RPN; ++r)
#pragma unroll
    for (int q = 0; q < 4; ++q) acc[r][q] = 0.f;

  for (int k = 0; k < K; k += 4) {
    float xv[RPN][4];
#pragma unroll
    for (int r = 0; r < RPN; ++r)
      *reinterpret_cast<float4*>(xv[r]) =
          *reinterpret_cast<const float4*>(&xs[(r0 + r) * K + k]);
#pragma unroll
    for (int j = 0; j < 4; ++j) {
      float wv[4];
      *reinterpret_cast<float4*>(wv) =
          *reinterpret_cast<const float4*>(&W[(size_t)(k + j) * M + c4]);
#pragma unroll
      for (int r = 0; r < RPN; ++r)
#pragma unroll
        for (int q = 0; q < 4; ++q)
          acc[r][q] = fmaf(xv[r][j], wv[q], acc[r][q]);
    }
  }
  float bv[4];
  *reinterpret_cast<float4*>(bv) = *reinterpret_cast<const float4*>(&bias[c4]);
#pragma unroll
  for (int r = 0; r < RPN; ++r) {
    float o[4];
#pragma unroll
    for (int q = 0; q < 4; ++q) o[q] = acc[r][q] + bv[q];
    *reinterpret_cast<float4*>(&Y[(size_t)(n0 + r0 + r) * M + c4]) =
        *reinterpret_cast<float4*>(o);
  }
}

// ---------- bucketed CSR build: key = dst*NB + src/bdiv ----------
__global__ void hist_b(const int* __restrict__ ei, int* __restrict__ kcnt,
                       int E, int bdiv) {
  int i = blockIdx.x * blockDim.x + threadIdx.x;
  if (i < E) atomicAdd(&kcnt[ei[E + i] * NB + ei[i] / bdiv], 1);
}

__global__ __launch_bounds__(1024) void blk_scan(
    const int* __restrict__ in, int* __restrict__ out1, int* __restrict__ bsum, int n) {
  __shared__ int buf[1024];
  const int tid = threadIdx.x;
  const int gid = blockIdx.x * 1024 + tid;
  int v = (gid < n) ? in[gid] : 0;
  buf[tid] = v;
  __syncthreads();
  for (int off = 1; off < 1024; off <<= 1) {
    int t = (tid >= off) ? buf[tid - off] : 0;
    __syncthreads();
    buf[tid] += t;
    __syncthreads();
  }
  if (gid < n) out1[gid] = buf[tid];
  if (tid == 1023) bsum[blockIdx.x] = buf[1023];
}

__global__ void scan_bsum(int* __restrict__ bsum, int nb) {
  if (blockIdx.x == 0 && threadIdx.x == 0) {
    int a = 0;
    for (int i = 0; i < nb; ++i) { a += bsum[i]; bsum[i] = a; }
  }
}

__global__ void add_off(int* __restrict__ kptr, const int* __restrict__ bsum, int n) {
  int gid = blockIdx.x * blockDim.x + threadIdx.x;
  if (gid == 0) kptr[0] = 0;
  if (gid < n) {
    int blk = gid >> 10;
    if (blk > 0) kptr[1 + gid] += bsum[blk - 1];
  }
}

__global__ void csr_fill_b(const int* __restrict__ ei, const int* __restrict__ kptr,
                           int* __restrict__ kfill, int* __restrict__ csr_src,
                           int* __restrict__ csr_eid, int E, int bdiv) {
  int i = blockIdx.x * blockDim.x + threadIdx.x;
  if (i < E) {
    int src = ei[i], dst = ei[E + i];
    int key = dst * NB + src / bdiv;
    int slot = kptr[key] + atomicAdd(&kfill[key], 1);
    csr_src[slot] = src;
    csr_eid[slot] = i;
  }
}

// permute edge_attr rows into CSR order (streamed scalar reads in the fused kernel)
__global__ void ea_perm(const float* __restrict__ ea, const int* __restrict__ csr_eid,
                        float* __restrict__ ea_csr, int E) {
  int i = blockIdx.x * blockDim.x + threadIdx.x;
  if (i < E * 16) {
    int slot = i >> 4;
    ea_csr[i] = ea[((size_t)csr_eid[slot] << 4) + (i & 15)];
  }
}

// ---------- one edge of fused GATv2 with SGPR-resident ea coefficients ----------
template <int GS>
__device__ __forceinline__ void gat_edge_s(
    const float4 a, const float (&c)[16], const float4 xv,
    const float (&wef)[16][4], const float (&attv)[4],
    float& m, float& s, float (&acc)[4]) {
  float mv[4] = {a.x + xv.x, a.y + xv.y, a.z + xv.z, a.w + xv.w};
#pragma unroll
  for (int k = 0; k < 16; ++k) {
#pragma unroll
    for (int q = 0; q < 4; ++q) mv[q] = fmaf(c[k], wef[k][q], mv[q]);
  }
  float l = 0.f;
#pragma unroll
  for (int q = 0; q < 4; ++q) {
    const float v = fmaxf(mv[q], 0.2f * mv[q]);  // leaky-relu
    l = fmaf(v, attv[q], l);
  }
#pragma unroll
  for (int off = 1; off < GS; off <<= 1) l += __shfl_xor(l, off);
  const float nm = fmaxf(m, l);
  const float sc = __expf(m - nm);
  const float pe = __expf(l - nm);
  m = nm;
  s = fmaf(s, sc, pe);
  acc[0] = fmaf(pe, a.x, acc[0] * sc);
  acc[1] = fmaf(pe, a.y, acc[1] * sc);
  acc[2] = fmaf(pe, a.z, acc[2] * sc);
  acc[3] = fmaf(pe, a.w, acc[3] * sc);
}

// ---------- fused per-dst GATv2: wave-per-dst, scalar edge metadata ----------
// One wave owns one dst (256-column slab selected by colbase). Edge index p,
// src id, and the 16-float ea row are wave-uniform -> scalar loads (s_load),
// SGPR operands in the FMA chain. Gather pipeline: 4 xl rows in flight.
// MODE 0: concat -> out[dst*HCROW + col0] = acc/s + bias
// MODE 1: head-pair partial mean -> out[dst*128 + lane*4] (lanes 0..31)
template <int HCROW, int MODE>
__global__ __launch_bounds__(256) void fused_gat(
    const float* __restrict__ xl, const float* __restrict__ xr,
    const float* __restrict__ ea_csr, const float* __restrict__ We,
    const float* __restrict__ att, const float* __restrict__ bias,
    const int* __restrict__ kptr, const int* __restrict__ csr_src,
    float* __restrict__ out, int N, int colbase) {
  constexpr int C = HCROW / 4;   // per-head dim (64 or 128)
  constexpr int GS = C / 4;      // lanes per head group (16 or 32)
  const int lane = threadIdx.x & 63;
  const int wslot = threadIdx.x >> 6;
  const int dst = blockIdx.x * 4 + wslot;
  if (dst >= N) return;

  float wef[16][4];
#pragma unroll
  for (int k = 0; k < 16; ++k)
    *reinterpret_cast<float4*>(wef[k]) =
        *reinterpret_cast<const float4*>(&We[k * HCROW + colbase + lane * 4]);
  const int col0 = colbase + lane * 4;
  const int head = col0 / C;
  float attv[4];
  *reinterpret_cast<float4*>(attv) =
      *reinterpret_cast<const float4*>(&att[head * C + (col0 % C)]);
  const float4* xl4 = reinterpret_cast<const float4*>(xl);
  const int rs4 = HCROW / 4;
  const int coff = col0 >> 2;
  const float4 xrv =
      reinterpret_cast<const float4*>(xr)[(size_t)dst * rs4 + coff];

  // wave-uniform row range (readfirstlane anchors uniformity -> s_load chain)
  const int row0 = __builtin_amdgcn_readfirstlane(kptr[dst * NB]);
  const int rend = __builtin_amdgcn_readfirstlane(kptr[dst * NB + NB]);

  float m = -__builtin_inff(), s = 0.f;
  float acc[4] = {0.f, 0.f, 0.f, 0.f};

  if (row0 < rend) {
    const int last = rend - 1;
    // prologue: 4 gather rows in flight, current ea pair, src pair for p+4/5
    const int s0 = csr_src[row0];
    const int s1 = csr_src[min(row0 + 1, last)];
    const int s2 = csr_src[min(row0 + 2, last)];
    const int s3 = csr_src[min(row0 + 3, last)];
    float4 a0 = xl4[(size_t)s0 * rs4 + coff];
    float4 a1 = xl4[(size_t)s1 * rs4 + coff];
    float4 a2 = xl4[(size_t)s2 * rs4 + coff];
    float4 a3 = xl4[(size_t)s3 * rs4 + coff];
    int sr0 = csr_src[min(row0 + 4, last)];
    int sr1 = csr_src[min(row0 + 5, last)];
    float c0[16], c1[16];
    {
      const float* e0 = ea_csr + (size_t)row0 * 16;
      const float* e1 = ea_csr + (size_t)min(row0 + 1, last) * 16;
#pragma unroll
      for (int k = 0; k < 16; ++k) { c0[k] = e0[k]; c1[k] = e1[k]; }
    }

    for (int p = row0; p < rend; p += 2) {
      // 1) issue gathers for p+4/p+5 with ALREADY-resident src ids (no wait)
      const float4 na0 = xl4[(size_t)sr0 * rs4 + coff];
      const float4 na1 = xl4[(size_t)sr1 * rs4 + coff];
      // 2) issue scalar loads: srcs for p+6/p+7, ea rows for p+2/p+3
      const int nsr0 = csr_src[min(p + 6, last)];
      const int nsr1 = csr_src[min(p + 7, last)];
      float cn0[16], cn1[16];
      {
        const float* e0 = ea_csr + (size_t)min(p + 2, last) * 16;
        const float* e1 = ea_csr + (size_t)min(p + 3, last) * 16;
#pragma unroll
        for (int k = 0; k < 16; ++k) { cn0[k] = e0[k]; cn1[k] = e1[k]; }
      }
      // 3) compute edges p, p+1 (covers the loads above)
      gat_edge_s<GS>(a0, c0, xrv, wef, attv, m, s, acc);
      if (p + 1 < rend) gat_edge_s<GS>(a1, c1, xrv, wef, attv, m, s, acc);
      // 4) rotate pipeline
      a0 = a2; a1 = a3; a2 = na0; a3 = na1;
      sr0 = nsr0; sr1 = nsr1;
#pragma unroll
      for (int k = 0; k < 16; ++k) { c0[k] = cn0[k]; c1[k] = cn1[k]; }
    }
  }

  const float inv = 1.f / (s + 1e-16f);
  float o[4];
  if (MODE == 0) {
    float bv[4];
    *reinterpret_cast<float4*>(bv) = *reinterpret_cast<const float4*>(&bias[col0]);
#pragma unroll
    for (int q = 0; q < 4; ++q) o[q] = fmaf(acc[q], inv, bv[q]);
    *reinterpret_cast<float4*>(&out[(size_t)dst * HCROW + col0]) =
        *reinterpret_cast<float4*>(o);
  } else {
#pragma unroll
    for (int q = 0; q < 4; ++q) {
      o[q] = acc[q] * inv;
      o[q] += __shfl_xor(o[q], 32);  // combine the slab's two heads
    }
    if (lane < 32)
      *reinterpret_cast<float4*>(&out[(size_t)dst * 128 + lane * 4]) =
          *reinterpret_cast<float4*>(o);
  }
}

// ---------- pooling (mean-over-heads + bias fused in) ----------
__global__ void pool_scatter(const float* __restrict__ hA, const float* __restrict__ hB,
                             const float* __restrict__ bias2, const int* __restrict__ batch,
                             unsigned* __restrict__ pmax, float* __restrict__ psum,
                             float* __restrict__ cnt, int N) {
  int idx = blockIdx.x * blockDim.x + threadIdx.x;
  if (idx >= N * 128) return;
  int n = idx >> 7, c = idx & 127;
  int g = batch[n];
  float v = 0.25f * (hA[idx] + hB[idx]) + bias2[c];
  atomicMax(&pmax[g * 128 + c], fmap(v));
  atomicAdd(&psum[g * 128 + c], v);
  if (c == 0) atomicAdd(&cnt[g], 1.f);
}

__global__ void pool_final(const unsigned* __restrict__ pmax, const float* __restrict__ psum,
                           const float* __restrict__ cnt, float* __restrict__ out) {
  int idx = blockIdx.x * blockDim.x + threadIdx.x;
  if (idx >= 64 * 128) return;
  int g = idx >> 7, c = idx & 127;
  float cg = cnt[g];
  out[g * 256 + c] = (cg > 0.f) ? funmap(pmax[idx]) : 0.f;
  out[g * 256 + 128 + c] = psum[idx] / fmaxf(cg, 1.f);
}

extern "C" void kernel_launch(void* const* d_in, const int* in_sizes, int n_in,
                              void* d_out, int out_size, void* d_ws, size_t ws_size,
                              hipStream_t stream) {
  const float* x     = (const float*)d_in[0];
  const float* ea    = (const float*)d_in[1];
  const int*   ei    = (const int*)d_in[2];
  const int*   batch = (const int*)d_in[3];
  const int N = in_sizes[0] / 128;  // 20000
  const int E = in_sizes[2] / 2;    // 640000
  const int NBINS = N * NB;
  const int bdiv = (N + NB - 1) / NB;  // 2500

  const float* Wl[3]   = {(const float*)d_in[4],  (const float*)d_in[11], (const float*)d_in[18]};
  const float* blv[3]  = {(const float*)d_in[5],  (const float*)d_in[12], (const float*)d_in[19]};
  const float* Wr[3]   = {(const float*)d_in[6],  (const float*)d_in[13], (const float*)d_in[20]};
  const float* brv[3]  = {(const float*)d_in[7],  (const float*)d_in[14], (const float*)d_in[21]};
  const float* Wev[3]  = {(const float*)d_in[8],  (const float*)d_in[15], (const float*)d_in[22]};
  const float* attv[3] = {(const float*)d_in[9],  (const float*)d_in[16], (const float*)d_in[23]};
  const float* bias[3] = {(const float*)d_in[10], (const float*)d_in[17], (const float*)d_in[24]};

  // ---- workspace layout (floats) ----
  float* ws = (float*)d_ws;
  float* xl     = ws;                          // N*512
  float* xr     = xl + (size_t)N * 512;        // N*512
  float* ea_csr = xr + (size_t)N * 512;        // E*16
  float* h      = ea_csr + (size_t)E * 16;     // N*256 (aliased: build ints / hsumA,B)
  int* kptr     = (int*)(h + (size_t)N * 256); // NBINS+1
  int* csr_src  = kptr + (NBINS + 1);          // E
  int* bsum     = csr_src + E;                 // <=257
  unsigned* pmax = (unsigned*)(bsum + 257);    // 64*128
  float* psum   = (float*)(pmax + 64 * 128);   // 64*128
  float* cnt    = psum + 64 * 128;             // 64
  // build-time temps aliased inside h (dead before h is first written):
  int* csr_eid = (int*)h;                      // E
  int* kcnt    = csr_eid + E;                  // NBINS
  int* kfill   = kcnt + NBINS;                 // NBINS
  // layer-2 head-pair partial sums aliased inside h (h dead after L2 GEMMs):
  float* hsumA = h;                            // N*128
  float* hsumB = h + (size_t)N * 128;          // N*128
  (void)n_in; (void)out_size; (void)ws_size;

  const int nodeBlocks = N / 16;
  const int edgeBlocks = (E + 255) / 256;
  const int scanBlocks = (NBINS + 1023) / 1024;
  const int gatBlocks = (N + 3) / 4;  // 4 waves/block, wave-per-dst

  // ---- bucketed CSR build ----
  hipMemsetAsync(kcnt, 0, (size_t)2 * NBINS * sizeof(int), stream);  // kcnt+kfill
  hist_b<<<edgeBlocks, 256, 0, stream>>>(ei, kcnt, E, bdiv);
  blk_scan<<<scanBlocks, 1024, 0, stream>>>(kcnt, kptr + 1, bsum, NBINS);
  scan_bsum<<<1, 64, 0, stream>>>(bsum, scanBlocks);
  add_off<<<(NBINS + 255) / 256, 256, 0, stream>>>(kptr, bsum, NBINS);
  csr_fill_b<<<edgeBlocks, 256, 0, stream>>>(ei, kptr, kfill, csr_src, csr_eid, E, bdiv);
  ea_perm<<<(E * 16 + 255) / 256, 256, 0, stream>>>(ea, csr_eid, ea_csr, E);

  // ================= layer 0 (K=128 -> hc=256, concat) =================
  node_gemm<128, 256><<<nodeBlocks, 256, 0, stream>>>(x, Wl[0], blv[0], xl);
  node_gemm<128, 256><<<nodeBlocks, 256, 0, stream>>>(x, Wr[0], brv[0], xr);
  fused_gat<256, 0><<<gatBlocks, 256, 0, stream>>>(
      xl, xr, ea_csr, Wev[0], attv[0], bias[0], kptr, csr_src, h, N, 0);

  // ================= layer 1 (K=256 -> hc=256, concat) =================
  node_gemm<256, 256><<<nodeBlocks, 256, 0, stream>>>(h, Wl[1], blv[1], xl);
  node_gemm<256, 256><<<nodeBlocks, 256, 0, stream>>>(h, Wr[1], brv[1], xr);
  fused_gat<256, 0><<<gatBlocks, 256, 0, stream>>>(
      xl, xr, ea_csr, Wev[1], attv[1], bias[1], kptr, csr_src, h, N, 0);

  // ================= layer 2 (K=256 -> hc=512, mean over heads) =================
  node_gemm<256, 512><<<nodeBlocks, 256, 0, stream>>>(h, Wl[2], blv[2], xl);
  node_gemm<256, 512><<<nodeBlocks, 256, 0, stream>>>(h, Wr[2], brv[2], xr);
  // two column-half dispatches; each writes head-pair partial means
  fused_gat<512, 1><<<gatBlocks, 256, 0, stream>>>(
      xl, xr, ea_csr, Wev[2], attv[2], bias[2], kptr, csr_src, hsumA, N, 0);
  fused_gat<512, 1><<<gatBlocks, 256, 0, stream>>>(
      xl, xr, ea_csr, Wev[2], attv[2], bias[2], kptr, csr_src, hsumB, N, 256);

  // ================= pooling (mean-over-heads fused) =================
  hipMemsetAsync(pmax, 0, (size_t)(64 * 128 * 2 + 64) * sizeof(float), stream);
  pool_scatter<<<(N * 128 + 255) / 256, 256, 0, stream>>>(hsumA, hsumB, bias[2], batch,
                                                          pmax, psum, cnt, N);
  pool_final<<<(64 * 128 + 255) / 256, 256, 0, stream>>>(pmax, psum, cnt, (float*)d_out);
}

// Round 7
// 1107.167 us; speedup vs baseline: 2.2333x; 1.0103x over previous
//
#include <hip/hip_runtime.h>

#define NB 8  // src buckets: edges of each dst are stored bucket-sorted

// ---------- node GEMM: Y[N,M] = X[N,K] @ W[K,M] + b ----------
template <int K, int M>
__global__ __launch_bounds__(256) void node_gemm(
    const float* __restrict__ X, const float* __restrict__ W,
    const float* __restrict__ bias, float* __restrict__ Y) {
  constexpr int NPB = 16;
  constexpr int COLS4 = M / 4;
  constexpr int NG = 256 / COLS4;
  constexpr int RPN = NPB / NG;
  __shared__ float xs[NPB * K];
  const int tid = threadIdx.x;
  const int n0 = blockIdx.x * NPB;
  {
    const float4* X4 = reinterpret_cast<const float4*>(X + (size_t)n0 * K);
    float4* xs4 = reinterpret_cast<float4*>(xs);
    for (int i = tid; i < NPB * K / 4; i += 256) xs4[i] = X4[i];
  }
  __syncthreads();
  const int c4 = (tid % COLS4) * 4;
  const int r0 = (tid / COLS4) * RPN;
  float acc[RPN][4];
#pragma unroll
  for (int r = 0; r < RPN; ++r)
#pragma unroll
    for (int q = 0; q < 4; ++q) acc[r][q] = 0.f;

  for (int k = 0; k < K; k += 4) {
    float xv[RPN][4];
#pragma unroll
    for (int r = 0; r < RPN; ++r)
      *reinterpret_cast<float4*>(xv[r]) =
          *reinterpret_cast<const float4*>(&xs[(r0 + r) * K + k]);
#pragma unroll
    for (int j = 0; j < 4; ++j) {
      float wv[4];
      *reinterpret_cast<float4*>(wv) =
          *reinterpret_cast<const float4*>(&W[(size_t)(k + j) * M + c4]);
#pragma unroll
      for (int r = 0; r < RPN; ++r)
#pragma unroll
        for (int q = 0; q < 4; ++q)
          acc[r][q] = fmaf(xv[r][j], wv[q], acc[r][q]);
    }
  }
  float bv[4];
  *reinterpret_cast<float4*>(bv) = *reinterpret_cast<const float4*>(&bias[c4]);
#pragma unroll
  for (int r = 0; r < RPN; ++r) {
    float o[4];
#pragma unroll
    for (int q = 0; q < 4; ++q) o[q] = acc[r][q] + bv[q];
    *reinterpret_cast<float4*>(&Y[(size_t)(n0 + r0 + r) * M + c4]) =
        *reinterpret_cast<float4*>(o);
  }
}

// ---------- bucketed CSR build: key = dst*NB + src/bdiv ----------
__global__ void hist_b(const int* __restrict__ ei, int* __restrict__ kcnt,
                       int E, int bdiv) {
  int i = blockIdx.x * blockDim.x + threadIdx.x;
  if (i < E) atomicAdd(&kcnt[ei[E + i] * NB + ei[i] / bdiv], 1);
}

__global__ __launch_bounds__(1024) void blk_scan(
    const int* __restrict__ in, int* __restrict__ out1, int* __restrict__ bsum, int n) {
  __shared__ int buf[1024];
  const int tid = threadIdx.x;
  const int gid = blockIdx.x * 1024 + tid;
  int v = (gid < n) ? in[gid] : 0;
  buf[tid] = v;
  __syncthreads();
  for (int off = 1; off < 1024; off <<= 1) {
    int t = (tid >= off) ? buf[tid - off] : 0;
    __syncthreads();
    buf[tid] += t;
    __syncthreads();
  }
  if (gid < n) out1[gid] = buf[tid];
  if (tid == 1023) bsum[blockIdx.x] = buf[1023];
}

__global__ void scan_bsum(int* __restrict__ bsum, int nb) {
  if (blockIdx.x == 0 && threadIdx.x == 0) {
    int a = 0;
    for (int i = 0; i < nb; ++i) { a += bsum[i]; bsum[i] = a; }
  }
}

__global__ void add_off(int* __restrict__ kptr, const int* __restrict__ bsum, int n) {
  int gid = blockIdx.x * blockDim.x + threadIdx.x;
  if (gid == 0) kptr[0] = 0;
  if (gid < n) {
    int blk = gid >> 10;
    if (blk > 0) kptr[1 + gid] += bsum[blk - 1];
  }
}

__global__ void csr_fill_b(const int* __restrict__ ei, const int* __restrict__ kptr,
                           int* __restrict__ kfill, int* __restrict__ csr_src,
                           int* __restrict__ csr_eid, int E, int bdiv) {
  int i = blockIdx.x * blockDim.x + threadIdx.x;
  if (i < E) {
    int src = ei[i], dst = ei[E + i];
    int key = dst * NB + src / bdiv;
    int slot = kptr[key] + atomicAdd(&kfill[key], 1);
    csr_src[slot] = src;
    csr_eid[slot] = i;
  }
}

// permute edge_attr rows into CSR order (streamed scalar reads in the fused kernel)
__global__ void ea_perm(const float* __restrict__ ea, const int* __restrict__ csr_eid,
                        float* __restrict__ ea_csr, int E) {
  int i = blockIdx.x * blockDim.x + threadIdx.x;
  if (i < E * 16) {
    int slot = i >> 4;
    ea_csr[i] = ea[((size_t)csr_eid[slot] << 4) + (i & 15)];
  }
}

// ---------- graph boundary detection (batch is sorted) ----------
__global__ void graph_bounds(const int* __restrict__ batch, int* __restrict__ gstart,
                             int* __restrict__ gend, int N) {
  int i = blockIdx.x * blockDim.x + threadIdx.x;
  if (i < N) {
    int g = batch[i];
    atomicMin(&gstart[g], i);
    atomicMax(&gend[g], i + 1);
  }
}

// ---------- one edge of fused GATv2 with SGPR-resident ea coefficients ----------
template <int GS>
__device__ __forceinline__ void gat_edge_s(
    const float4 a, const float (&c)[16], const float4 xv,
    const float (&wef)[16][4], const float (&attv)[4],
    float& m, float& s, float (&acc)[4]) {
  float mv[4] = {a.x + xv.x, a.y + xv.y, a.z + xv.z, a.w + xv.w};
#pragma unroll
  for (int k = 0; k < 16; ++k) {
#pragma unroll
    for (int q = 0; q < 4; ++q) mv[q] = fmaf(c[k], wef[k][q], mv[q]);
  }
  float l = 0.f;
#pragma unroll
  for (int q = 0; q < 4; ++q) {
    const float v = fmaxf(mv[q], 0.2f * mv[q]);  // leaky-relu
    l = fmaf(v, attv[q], l);
  }
#pragma unroll
  for (int off = 1; off < GS; off <<= 1) l += __shfl_xor(l, off);
  const float nm = fmaxf(m, l);
  const float sc = __expf(m - nm);
  const float pe = __expf(l - nm);
  m = nm;
  s = fmaf(s, sc, pe);
  acc[0] = fmaf(pe, a.x, acc[0] * sc);
  acc[1] = fmaf(pe, a.y, acc[1] * sc);
  acc[2] = fmaf(pe, a.z, acc[2] * sc);
  acc[3] = fmaf(pe, a.w, acc[3] * sc);
}

// ---------- fused per-dst GATv2: wave-per-dst, scalar edge metadata ----------
// One wave owns one dst (256-column slab). Edge index p, src id, and the
// 16-float ea row are wave-uniform -> scalar loads, SGPR operands in the FMA
// chain. Gather pipeline: 4 xl rows in flight.
// MODE 0: concat -> out[dst*HCROW + col0] = acc/s + bias  (grid = gb)
// MODE 1: layer-2 head-pair partial mean; grid = 2*gb: first half writes outA
//         (cols 0..255, heads 0/1), second half outB (cols 256..511, heads 2/3)
template <int HCROW, int MODE>
__global__ __launch_bounds__(256) void fused_gat(
    const float* __restrict__ xl, const float* __restrict__ xr,
    const float* __restrict__ ea_csr, const float* __restrict__ We,
    const float* __restrict__ att, const float* __restrict__ bias,
    const int* __restrict__ kptr, const int* __restrict__ csr_src,
    float* __restrict__ out, float* __restrict__ outB, int N) {
  constexpr int C = HCROW / 4;   // per-head dim (64 or 128)
  constexpr int GS = C / 4;      // lanes per head group (16 or 32)
  const int lane = threadIdx.x & 63;
  const int wslot = threadIdx.x >> 6;
  int bx = blockIdx.x;
  int colbase = 0;
  float* o_ptr = out;
  if (MODE == 1) {
    const int gb = gridDim.x >> 1;
    if (bx >= gb) { bx -= gb; colbase = 256; o_ptr = outB; }
  }
  const int dst = bx * 4 + wslot;
  if (dst >= N) return;

  float wef[16][4];
#pragma unroll
  for (int k = 0; k < 16; ++k)
    *reinterpret_cast<float4*>(wef[k]) =
        *reinterpret_cast<const float4*>(&We[k * HCROW + colbase + lane * 4]);
  const int col0 = colbase + lane * 4;
  const int head = col0 / C;
  float attv[4];
  *reinterpret_cast<float4*>(attv) =
      *reinterpret_cast<const float4*>(&att[head * C + (col0 % C)]);
  const float4* xl4 = reinterpret_cast<const float4*>(xl);
  const int rs4 = HCROW / 4;
  const int coff = col0 >> 2;
  const float4 xrv =
      reinterpret_cast<const float4*>(xr)[(size_t)dst * rs4 + coff];

  // wave-uniform row range (readfirstlane anchors uniformity -> s_load chain)
  const int row0 = __builtin_amdgcn_readfirstlane(kptr[dst * NB]);
  const int rend = __builtin_amdgcn_readfirstlane(kptr[dst * NB + NB]);

  float m = -__builtin_inff(), s = 0.f;
  float acc[4] = {0.f, 0.f, 0.f, 0.f};

  if (row0 < rend) {
    const int last = rend - 1;
    const int s0 = csr_src[row0];
    const int s1 = csr_src[min(row0 + 1, last)];
    const int s2 = csr_src[min(row0 + 2, last)];
    const int s3 = csr_src[min(row0 + 3, last)];
    float4 a0 = xl4[(size_t)s0 * rs4 + coff];
    float4 a1 = xl4[(size_t)s1 * rs4 + coff];
    float4 a2 = xl4[(size_t)s2 * rs4 + coff];
    float4 a3 = xl4[(size_t)s3 * rs4 + coff];
    int sr0 = csr_src[min(row0 + 4, last)];
    int sr1 = csr_src[min(row0 + 5, last)];
    float c0[16], c1[16];
    {
      const float* e0 = ea_csr + (size_t)row0 * 16;
      const float* e1 = ea_csr + (size_t)min(row0 + 1, last) * 16;
#pragma unroll
      for (int k = 0; k < 16; ++k) { c0[k] = e0[k]; c1[k] = e1[k]; }
    }

    for (int p = row0; p < rend; p += 2) {
      const float4 na0 = xl4[(size_t)sr0 * rs4 + coff];
      const float4 na1 = xl4[(size_t)sr1 * rs4 + coff];
      const int nsr0 = csr_src[min(p + 6, last)];
      const int nsr1 = csr_src[min(p + 7, last)];
      float cn0[16], cn1[16];
      {
        const float* e0 = ea_csr + (size_t)min(p + 2, last) * 16;
        const float* e1 = ea_csr + (size_t)min(p + 3, last) * 16;
#pragma unroll
        for (int k = 0; k < 16; ++k) { cn0[k] = e0[k]; cn1[k] = e1[k]; }
      }
      gat_edge_s<GS>(a0, c0, xrv, wef, attv, m, s, acc);
      if (p + 1 < rend) gat_edge_s<GS>(a1, c1, xrv, wef, attv, m, s, acc);
      a0 = a2; a1 = a3; a2 = na0; a3 = na1;
      sr0 = nsr0; sr1 = nsr1;
#pragma unroll
      for (int k = 0; k < 16; ++k) { c0[k] = cn0[k]; c1[k] = cn1[k]; }
    }
  }

  const float inv = 1.f / (s + 1e-16f);
  float o[4];
  if (MODE == 0) {
    float bv[4];
    *reinterpret_cast<float4*>(bv) = *reinterpret_cast<const float4*>(&bias[col0]);
#pragma unroll
    for (int q = 0; q < 4; ++q) o[q] = fmaf(acc[q], inv, bv[q]);
    *reinterpret_cast<float4*>(&o_ptr[(size_t)dst * HCROW + col0]) =
        *reinterpret_cast<float4*>(o);
  } else {
#pragma unroll
    for (int q = 0; q < 4; ++q) {
      o[q] = acc[q] * inv;
      o[q] += __shfl_xor(o[q], 32);  // combine the slab's two heads
    }
    if (lane < 32)
      *reinterpret_cast<float4*>(&o_ptr[(size_t)dst * 128 + lane * 4]) =
          *reinterpret_cast<float4*>(o);
  }
}

// ---------- pooling: one block per graph, no atomics ----------
// h = 0.25*(hA+hB) + bias; out[g] = [max over nodes, mean over nodes]
__global__ __launch_bounds__(256) void pool_graph(
    const float* __restrict__ hA, const float* __restrict__ hB,
    const float* __restrict__ bias2, const int* __restrict__ gstart,
    const int* __restrict__ gend, float* __restrict__ out) {
  const int g = blockIdx.x;
  const int c = threadIdx.x & 127;
  const int sub = threadIdx.x >> 7;
  const int s0 = gstart[g], e0 = gend[g];
  const float b = bias2[c];
  float mx = -__builtin_inff(), sm = 0.f;
  for (int n = s0 + sub; n < e0; n += 2) {
    const float v = fmaf(0.25f, hA[(size_t)n * 128 + c] + hB[(size_t)n * 128 + c], b);
    mx = fmaxf(mx, v);
    sm += v;
  }
  __shared__ float smx[128], ssm[128];
  if (sub) { smx[c] = mx; ssm[c] = sm; }
  __syncthreads();
  if (!sub) {
    mx = fmaxf(mx, smx[c]);
    sm += ssm[c];
    const int cnt = e0 - s0;
    out[g * 256 + c] = (cnt > 0) ? mx : 0.f;
    out[g * 256 + 128 + c] = sm / fmaxf((float)cnt, 1.f);
  }
}

extern "C" void kernel_launch(void* const* d_in, const int* in_sizes, int n_in,
                              void* d_out, int out_size, void* d_ws, size_t ws_size,
                              hipStream_t stream) {
  const float* x     = (const float*)d_in[0];
  const float* ea    = (const float*)d_in[1];
  const int*   ei    = (const int*)d_in[2];
  const int*   batch = (const int*)d_in[3];
  const int N = in_sizes[0] / 128;  // 20000
  const int E = in_sizes[2] / 2;    // 640000
  const int NBINS = N * NB;
  const int bdiv = (N + NB - 1) / NB;  // 2500

  const float* Wl[3]   = {(const float*)d_in[4],  (const float*)d_in[11], (const float*)d_in[18]};
  const float* blv[3]  = {(const float*)d_in[5],  (const float*)d_in[12], (const float*)d_in[19]};
  const float* Wr[3]   = {(const float*)d_in[6],  (const float*)d_in[13], (const float*)d_in[20]};
  const float* brv[3]  = {(const float*)d_in[7],  (const float*)d_in[14], (const float*)d_in[21]};
  const float* Wev[3]  = {(const float*)d_in[8],  (const float*)d_in[15], (const float*)d_in[22]};
  const float* attv[3] = {(const float*)d_in[9],  (const float*)d_in[16], (const float*)d_in[23]};
  const float* bias[3] = {(const float*)d_in[10], (const float*)d_in[17], (const float*)d_in[24]};

  // ---- workspace layout (floats) ----
  float* ws = (float*)d_ws;
  float* xl     = ws;                          // N*512
  float* xr     = xl + (size_t)N * 512;        // N*512
  float* ea_csr = xr + (size_t)N * 512;        // E*16
  float* h      = ea_csr + (size_t)E * 16;     // N*256 (aliased: build ints / hsumA,B)
  int* kptr     = (int*)(h + (size_t)N * 256); // NBINS+1
  int* csr_src  = kptr + (NBINS + 1);          // E
  int* bsum     = csr_src + E;                 // <=257
  int* gstart   = bsum + 257;                  // 64
  int* gend     = gstart + 64;                 // 64
  // build-time temps aliased inside h (dead before h is first written):
  int* csr_eid = (int*)h;                      // E
  int* kcnt    = csr_eid + E;                  // NBINS
  int* kfill   = kcnt + NBINS;                 // NBINS
  // layer-2 head-pair partial sums aliased inside h (h dead after L2 GEMMs):
  float* hsumA = h;                            // N*128
  float* hsumB = h + (size_t)N * 128;          // N*128
  (void)n_in; (void)out_size; (void)ws_size;

  const int nodeBlocks = N / 16;
  const int edgeBlocks = (E + 255) / 256;
  const int scanBlocks = (NBINS + 1023) / 1024;
  const int gatBlocks = (N + 3) / 4;  // 4 waves/block, wave-per-dst

  // ---- bucketed CSR build + graph bounds ----
  hipMemsetAsync(kcnt, 0, (size_t)2 * NBINS * sizeof(int), stream);  // kcnt+kfill
  hipMemsetAsync(gstart, 0x7f, 64 * sizeof(int), stream);            // ~INT_MAX
  hipMemsetAsync(gend, 0, 64 * sizeof(int), stream);
  hist_b<<<edgeBlocks, 256, 0, stream>>>(ei, kcnt, E, bdiv);
  graph_bounds<<<(N + 255) / 256, 256, 0, stream>>>(batch, gstart, gend, N);
  blk_scan<<<scanBlocks, 1024, 0, stream>>>(kcnt, kptr + 1, bsum, NBINS);
  scan_bsum<<<1, 64, 0, stream>>>(bsum, scanBlocks);
  add_off<<<(NBINS + 255) / 256, 256, 0, stream>>>(kptr, bsum, NBINS);
  csr_fill_b<<<edgeBlocks, 256, 0, stream>>>(ei, kptr, kfill, csr_src, csr_eid, E, bdiv);
  ea_perm<<<(E * 16 + 255) / 256, 256, 0, stream>>>(ea, csr_eid, ea_csr, E);

  // ================= layer 0 (K=128 -> hc=256, concat) =================
  node_gemm<128, 256><<<nodeBlocks, 256, 0, stream>>>(x, Wl[0], blv[0], xl);
  node_gemm<128, 256><<<nodeBlocks, 256, 0, stream>>>(x, Wr[0], brv[0], xr);
  fused_gat<256, 0><<<gatBlocks, 256, 0, stream>>>(
      xl, xr, ea_csr, Wev[0], attv[0], bias[0], kptr, csr_src, h, nullptr, N);

  // ================= layer 1 (K=256 -> hc=256, concat) =================
  node_gemm<256, 256><<<nodeBlocks, 256, 0, stream>>>(h, Wl[1], blv[1], xl);
  node_gemm<256, 256><<<nodeBlocks, 256, 0, stream>>>(h, Wr[1], brv[1], xr);
  fused_gat<256, 0><<<gatBlocks, 256, 0, stream>>>(
      xl, xr, ea_csr, Wev[1], attv[1], bias[1], kptr, csr_src, h, nullptr, N);

  // ================= layer 2 (K=256 -> hc=512, mean over heads) =================
  node_gemm<256, 512><<<nodeBlocks, 256, 0, stream>>>(h, Wl[2], blv[2], xl);
  node_gemm<256, 512><<<nodeBlocks, 256, 0, stream>>>(h, Wr[2], brv[2], xr);
  // single dispatch covers both column halves (first half -> hsumA, second -> hsumB)
  fused_gat<512, 1><<<2 * gatBlocks, 256, 0, stream>>>(
      xl, xr, ea_csr, Wev[2], attv[2], bias[2], kptr, csr_src, hsumA, hsumB, N);

  // ================= pooling (mean-over-heads + bias fused, no atomics) ==========
  pool_graph<<<64, 256, 0, stream>>>(hsumA, hsumB, bias[2], gstart, gend, (float*)d_out);
}